// Round 3
// baseline (1014.058 us; speedup 1.0000x reference)
//
#include <hip/hip_runtime.h>
#include <cstdint>

#define Bc 256
#define Cc 64
#define Hc 128
#define Oc 64
#define Tc 512

typedef short bf16x8 __attribute__((ext_vector_type(8)));
typedef float f32x4 __attribute__((ext_vector_type(4)));
typedef _Float16 f16x8 __attribute__((ext_vector_type(8)));
typedef _Float16 h4 __attribute__((ext_vector_type(4)));

static __device__ __forceinline__ unsigned short f2b(float f) {
  unsigned u = __float_as_uint(f);
  unsigned r = u + 0x7FFFu + ((u >> 16) & 1u);   // RNE
  return (unsigned short)(r >> 16);
}

static __device__ __forceinline__ float sigf(float x) {
  return 1.f / (1.f + __expf(-x));   // overflow-safe: exp->inf -> 0
}

// Opaque register pin: the asm may "modify" v, so the compiler cannot
// rematerialize it from memory — it must stay live in VGPRs across the loop.
static __device__ __forceinline__ void keep(f16x8& v) {
  asm volatile("" : "+v"(v));
}

// ---------------------------------------------------------------------------
// K0: weight prep.
//  wdgT [192][64] bf16, w2T [384][128] bf16, hyT [64][128] bf16
//  whT  [3][128][128] fp16: [g][j][k] = w_h*[k][j]   (B-fragment layout)
// ---------------------------------------------------------------------------
__global__ __launch_bounds__(256) void k_wprep(
    const float* __restrict__ w_dg_x, const float* __restrict__ w_dg_h,
    const float* __restrict__ w_xz, const float* __restrict__ w_mz,
    const float* __restrict__ w_xr, const float* __restrict__ w_mr,
    const float* __restrict__ w_xh, const float* __restrict__ w_mh,
    const float* __restrict__ w_hy,
    const float* __restrict__ w_hz, const float* __restrict__ w_hr,
    const float* __restrict__ w_hh,
    unsigned short* __restrict__ wdgT, unsigned short* __restrict__ w2T,
    unsigned short* __restrict__ hyT, _Float16* __restrict__ whT) {
  int e = blockIdx.x * 256 + threadIdx.x;
  if (e < 12288) {                       // wdgT: 192 x 64
    int n = e >> 6, k = e & 63;
    float v = (n < 64) ? w_dg_x[k * Cc + n] : w_dg_h[k * Hc + (n - 64)];
    wdgT[e] = f2b(v);
  } else if (e < 61440) {                // w2T: 384 x 128
    int i = e - 12288;
    int n = i >> 7, k = i & 127;
    int gate = n >> 7, nc = n & 127;
    const float* wx = (gate == 0) ? w_xz : (gate == 1) ? w_xr : w_xh;
    const float* wm = (gate == 0) ? w_mz : (gate == 1) ? w_mr : w_mh;
    float v = (k < 64) ? wx[k * Hc + nc] : wm[(k - 64) * Hc + nc];
    w2T[i] = f2b(v);
  } else if (e < 69632) {                // hyT: 64 x 128
    int i = e - 61440;
    int n = i >> 7, k = i & 127;
    hyT[i] = f2b(w_hy[k * Oc + n]);
  } else if (e < 118784) {               // whT: 3 x 128 x 128 fp16, [g][j][k]
    int i = e - 69632;
    int g = i >> 14, rem = i & 16383;
    int j = rem >> 7, k = rem & 127;
    const float* wh_ = (g == 0) ? w_hz : (g == 1) ? w_hr : w_hh;
    whT[i] = (_Float16)wh_[k * Hc + j];
  }
}

// ---------------------------------------------------------------------------
// K1: segmented x_last select-scan (unchanged).
// ---------------------------------------------------------------------------
__global__ __launch_bounds__(256) void k_scan(const float* __restrict__ input,
                                              const float* __restrict__ lastx,
                                              float* __restrict__ xlast) {
  const int b = blockIdx.x;
  const int seg = threadIdx.x >> 6;
  const int c = threadIdx.x & 63;
  const int tb = seg * 128;
  __shared__ float segval[4][64];
  __shared__ int   segvld[4][64];
  __shared__ float segcin[4][64];
  const float* xp = input + ((size_t)(b * 3 + 0) * Cc + c) * Tc;
  const float* mp = input + ((size_t)(b * 3 + 1) * Cc + c) * Tc;

  float val = 0.f; int vld = 0;
  for (int t = tb + 127; t >= tb; --t) {
    if (mp[t] > 0.f) { val = xp[t]; vld = 1; break; }
  }
  segval[seg][c] = val; segvld[seg][c] = vld;
  __syncthreads();
  if (threadIdx.x < 64) {
    float carry = lastx[b * Cc + threadIdx.x];
    #pragma unroll
    for (int s = 0; s < 4; ++s) {
      segcin[s][threadIdx.x] = carry;
      if (segvld[s][threadIdx.x]) carry = segval[s][threadIdx.x];
    }
  }
  __syncthreads();
  float cur = segcin[seg][c];
  float* op = xlast + ((size_t)b * Tc + tb) * Cc + c;
  for (int t = 0; t < 128; t += 4) {
    const float4 m4 = *reinterpret_cast<const float4*>(mp + tb + t);
    const float4 x4 = *reinterpret_cast<const float4*>(xp + tb + t);
    cur = (m4.x > 0.f) ? x4.x : cur; op[(size_t)(t + 0) * Cc] = cur;
    cur = (m4.y > 0.f) ? x4.y : cur; op[(size_t)(t + 1) * Cc] = cur;
    cur = (m4.z > 0.f) ? x4.z : cur; op[(size_t)(t + 2) * Cc] = cur;
    cur = (m4.w > 0.f) ? x4.w : cur; op[(size_t)(t + 3) * Cc] = cur;
  }
}

// ---------------------------------------------------------------------------
// K2: MFMA bf16 pre-compute. Output packed [t][b][H][4] fp16:
//  s=0 gamma_h, s=1 pre_z, s=2 pre_r, s=3 pre_h  (one dwordx2 per (b,col) in k_seq)
// ---------------------------------------------------------------------------
__global__ __launch_bounds__(256) void k_pre(
    const float* __restrict__ input, const float* __restrict__ x_mean,
    const float* __restrict__ xlast,
    const float* __restrict__ b_dg_x, const float* __restrict__ b_dg_h,
    const float* __restrict__ b_mz, const float* __restrict__ b_mh,
    const unsigned short* __restrict__ wdgT, const unsigned short* __restrict__ w2T,
    _Float16* __restrict__ P4) {
  __shared__ unsigned short d16[64 * 72];
  __shared__ unsigned short A16[64 * 136];
  __shared__ float x_cs[64 * 68];
  __shared__ float m_cs[64 * 68];

  const int tid = threadIdx.x;
  const int b = blockIdx.x >> 3;
  const int t0 = (blockIdx.x & 7) * 64;
  const int w = tid >> 6, lane = tid & 63, quad = lane >> 4, l16 = lane & 15;

  #pragma unroll
  for (int i = 0; i < 4; ++i) {
    int e = tid + i * 256;
    int c = e >> 4, t4 = (e & 15) * 4;
    const size_t rx = ((size_t)(b * 3 + 0) * Cc + c) * Tc + t0 + t4;
    const size_t rm = ((size_t)(b * 3 + 1) * Cc + c) * Tc + t0 + t4;
    const size_t rd = ((size_t)(b * 3 + 2) * Cc + c) * Tc + t0 + t4;
    float4 xv = *reinterpret_cast<const float4*>(input + rx);
    float4 mv = *reinterpret_cast<const float4*>(input + rm);
    float4 dv = *reinterpret_cast<const float4*>(input + rd);
    *reinterpret_cast<float4*>(&x_cs[c * 68 + t4]) = xv;
    *reinterpret_cast<float4*>(&m_cs[c * 68 + t4]) = mv;
    A16[(t4 + 0) * 136 + 64 + c] = f2b(mv.x);
    A16[(t4 + 1) * 136 + 64 + c] = f2b(mv.y);
    A16[(t4 + 2) * 136 + 64 + c] = f2b(mv.z);
    A16[(t4 + 3) * 136 + 64 + c] = f2b(mv.w);
    d16[(t4 + 0) * 72 + c] = f2b(dv.x);
    d16[(t4 + 1) * 72 + c] = f2b(dv.y);
    d16[(t4 + 2) * 72 + c] = f2b(dv.z);
    d16[(t4 + 3) * 72 + c] = f2b(dv.w);
  }
  __syncthreads();

  f32x4 accA[4][3];
  #pragma unroll
  for (int mt = 0; mt < 4; ++mt)
    #pragma unroll
    for (int j = 0; j < 3; ++j) accA[mt][j] = {0.f, 0.f, 0.f, 0.f};
  #pragma unroll
  for (int kt = 0; kt < 2; ++kt) {
    bf16x8 a[4];
    #pragma unroll
    for (int mt = 0; mt < 4; ++mt)
      a[mt] = *reinterpret_cast<const bf16x8*>(&d16[(mt * 16 + l16) * 72 + kt * 32 + quad * 8]);
    #pragma unroll
    for (int j = 0; j < 3; ++j) {
      int nt = w + j * 4;
      bf16x8 bb = *reinterpret_cast<const bf16x8*>(wdgT + (nt * 16 + l16) * 64 + kt * 32 + quad * 8);
      #pragma unroll
      for (int mt = 0; mt < 4; ++mt)
        accA[mt][j] = __builtin_amdgcn_mfma_f32_16x16x32_bf16(a[mt], bb, accA[mt][j], 0, 0, 0);
    }
  }

  {
    int c = w * 16 + l16;
    float xmn = x_mean[b * Cc + c];
    float bx = b_dg_x[c];
    #pragma unroll
    for (int mt = 0; mt < 4; ++mt)
      #pragma unroll
      for (int r = 0; r < 4; ++r) {
        int row = mt * 16 + quad * 4 + r;
        float g = __expf(-fmaxf(accA[mt][0][r] + bx, 0.f));
        float mv = m_cs[c * 68 + row], xv = x_cs[c * 68 + row];
        float xl = xlast[((size_t)b * Tc + t0 + row) * Cc + c];
        float xin = mv * xv + (1.f - mv) * (g * xl + (1.f - g) * xmn);
        A16[row * 136 + c] = f2b(xin);
      }
  }
  #pragma unroll
  for (int j = 1; j < 3; ++j) {
    int nh = (w + j * 4) * 16 - 64 + l16;
    float bh = b_dg_h[nh];
    #pragma unroll
    for (int mt = 0; mt < 4; ++mt)
      #pragma unroll
      for (int r = 0; r < 4; ++r) {
        int row = mt * 16 + quad * 4 + r;
        P4[(((size_t)(t0 + row) * Bc + b) * Hc + nh) * 4 + 0] =
            (_Float16)__expf(-fmaxf(accA[mt][j][r] + bh, 0.f));
      }
  }
  __syncthreads();

  f32x4 accB[4][6];
  #pragma unroll
  for (int mt = 0; mt < 4; ++mt)
    #pragma unroll
    for (int j = 0; j < 6; ++j) accB[mt][j] = {0.f, 0.f, 0.f, 0.f};
  #pragma unroll
  for (int kt = 0; kt < 4; ++kt) {
    bf16x8 a[4];
    #pragma unroll
    for (int mt = 0; mt < 4; ++mt)
      a[mt] = *reinterpret_cast<const bf16x8*>(&A16[(mt * 16 + l16) * 136 + kt * 32 + quad * 8]);
    #pragma unroll
    for (int j = 0; j < 6; ++j) {
      int nt = (j >> 1) * 8 + w + (j & 1) * 4;
      bf16x8 bb = *reinterpret_cast<const bf16x8*>(w2T + (nt * 16 + l16) * 128 + kt * 32 + quad * 8);
      #pragma unroll
      for (int mt = 0; mt < 4; ++mt)
        accB[mt][j] = __builtin_amdgcn_mfma_f32_16x16x32_bf16(a[mt], bb, accB[mt][j], 0, 0, 0);
    }
  }
  #pragma unroll
  for (int j = 0; j < 6; ++j) {
    int nt = (j >> 1) * 8 + w + (j & 1) * 4;
    int gate = nt >> 3;
    int col = (nt & 7) * 16 + l16;
    float bias = (gate == 0) ? b_mz[col] : (gate == 2) ? b_mh[col] : 0.f;
    #pragma unroll
    for (int mt = 0; mt < 4; ++mt)
      #pragma unroll
      for (int r = 0; r < 4; ++r) {
        int row = mt * 16 + quad * 4 + r;
        P4[(((size_t)(t0 + row) * Bc + b) * Hc + col) * 4 + gate + 1] =
            (_Float16)(accB[mt][j][r] + bias);
      }
  }
}

// ---------------------------------------------------------------------------
// K3: sequential h-recurrence, batched 16-wide on the matrix pipe.
// grid = 16 blocks x 512 threads (8 waves). Wave w owns output cols
// [w*16,w*16+16) for z, r AND h~ (gate combine is wave-local in MFMA C-layout).
// Weights pinned in 48 VGPRs/wave via keep(). 2 barriers/step, 12 MFMA/wave,
// each K=128 reduction split into two 2-deep MFMA chains + f32 add.
// Stream prefetch distance ~2.5 steps via two rotating h4[4] buffers.
// ---------------------------------------------------------------------------
__global__ __launch_bounds__(512, 1) void k_seq(
    const _Float16* __restrict__ P4,    // [T][B][H][4] fp16 {gamma,pz,pr,ph}
    const _Float16* __restrict__ whT,   // [3][128][128] fp16 [j][k]
    float* __restrict__ hs_out) {
  const int tid = threadIdx.x;
  const int w = tid >> 6, lane = tid & 63, quad = lane >> 4, l16 = lane & 15;
  const int b0 = blockIdx.x * 16;
  const int col = w * 16 + l16;

  __shared__ _Float16 hA[16 * 136];
  __shared__ _Float16 rA[16 * 136];

  // B-fragments: lane(l16)=col-within-tile, quad=k-octet, kt walks K=128.
  f16x8 bz[4], br[4], bh[4];
  #pragma unroll
  for (int kt = 0; kt < 4; ++kt) {
    int off = col * 128 + kt * 32 + quad * 8;
    bz[kt] = *reinterpret_cast<const f16x8*>(whT + off);
    br[kt] = *reinterpret_cast<const f16x8*>(whT + 16384 + off);
    bh[kt] = *reinterpret_cast<const f16x8*>(whT + 32768 + off);
  }

  for (int i = tid; i < 16 * 136; i += 512) hA[i] = (_Float16)0.f;

  const size_t strideT = (size_t)Bc * Hc * 4;
  const _Float16* pbase = P4 + ((size_t)(b0 + quad * 4) * Hc + col) * 4;

  float pz[4], pr[4], ph[4], hd[4];
  h4 s1[4], s2[4];
  #pragma unroll
  for (int ri = 0; ri < 4; ++ri) {
    h4 s = *reinterpret_cast<const h4*>(pbase + (size_t)ri * (Hc * 4));
    pz[ri] = (float)s[1]; pr[ri] = (float)s[2]; ph[ri] = (float)s[3];
    hd[ri] = 0.f;
  }
  #pragma unroll
  for (int ri = 0; ri < 4; ++ri)
    s1[ri] = *reinterpret_cast<const h4*>(pbase + strideT + (size_t)ri * (Hc * 4));
  #pragma unroll
  for (int ri = 0; ri < 4; ++ri)
    s2[ri] = *reinterpret_cast<const h4*>(pbase + 2 * strideT + (size_t)ri * (Hc * 4));

#define STEP(TT, SBUF)                                                          \
  do {                                                                          \
    __syncthreads(); /* hA(t) visible */                                        \
    f16x8 a0 = *reinterpret_cast<const f16x8*>(&hA[l16 * 136 + 0 * 32 + quad * 8]); \
    f16x8 a1 = *reinterpret_cast<const f16x8*>(&hA[l16 * 136 + 1 * 32 + quad * 8]); \
    f16x8 a2 = *reinterpret_cast<const f16x8*>(&hA[l16 * 136 + 2 * 32 + quad * 8]); \
    f16x8 a3 = *reinterpret_cast<const f16x8*>(&hA[l16 * 136 + 3 * 32 + quad * 8]); \
    f32x4 r0 = {pr[0], pr[1], pr[2], pr[3]};                                    \
    f32x4 r1 = {0.f, 0.f, 0.f, 0.f};                                            \
    r0 = __builtin_amdgcn_mfma_f32_16x16x32_f16(a0, br[0], r0, 0, 0, 0);        \
    r1 = __builtin_amdgcn_mfma_f32_16x16x32_f16(a1, br[1], r1, 0, 0, 0);        \
    r0 = __builtin_amdgcn_mfma_f32_16x16x32_f16(a2, br[2], r0, 0, 0, 0);        \
    r1 = __builtin_amdgcn_mfma_f32_16x16x32_f16(a3, br[3], r1, 0, 0, 0);        \
    f32x4 z0 = {pz[0], pz[1], pz[2], pz[3]};                                    \
    f32x4 z1 = {0.f, 0.f, 0.f, 0.f};                                            \
    z0 = __builtin_amdgcn_mfma_f32_16x16x32_f16(a0, bz[0], z0, 0, 0, 0);        \
    z1 = __builtin_amdgcn_mfma_f32_16x16x32_f16(a1, bz[1], z1, 0, 0, 0);        \
    z0 = __builtin_amdgcn_mfma_f32_16x16x32_f16(a2, bz[2], z0, 0, 0, 0);        \
    z1 = __builtin_amdgcn_mfma_f32_16x16x32_f16(a3, bz[3], z1, 0, 0, 0);        \
    _Pragma("unroll")                                                           \
    for (int ri = 0; ri < 4; ++ri) {                                            \
      float rr = sigf(r0[ri] + r1[ri]);                                         \
      rA[(quad * 4 + ri) * 136 + col] = (_Float16)(rr * hd[ri]);                \
    }                                                                           \
    float zs[4];                                                                \
    _Pragma("unroll")                                                           \
    for (int ri = 0; ri < 4; ++ri) zs[ri] = sigf(z0[ri] + z1[ri]);              \
    __syncthreads(); /* rA visible; hA reads done */                            \
    f16x8 c0 = *reinterpret_cast<const f16x8*>(&rA[l16 * 136 + 0 * 32 + quad * 8]); \
    f16x8 c1 = *reinterpret_cast<const f16x8*>(&rA[l16 * 136 + 1 * 32 + quad * 8]); \
    f16x8 c2 = *reinterpret_cast<const f16x8*>(&rA[l16 * 136 + 2 * 32 + quad * 8]); \
    f16x8 c3 = *reinterpret_cast<const f16x8*>(&rA[l16 * 136 + 3 * 32 + quad * 8]); \
    f32x4 h0 = {ph[0], ph[1], ph[2], ph[3]};                                    \
    f32x4 h1 = {0.f, 0.f, 0.f, 0.f};                                            \
    h0 = __builtin_amdgcn_mfma_f32_16x16x32_f16(c0, bh[0], h0, 0, 0, 0);        \
    h1 = __builtin_amdgcn_mfma_f32_16x16x32_f16(c1, bh[1], h1, 0, 0, 0);        \
    h0 = __builtin_amdgcn_mfma_f32_16x16x32_f16(c2, bh[2], h0, 0, 0, 0);        \
    h1 = __builtin_amdgcn_mfma_f32_16x16x32_f16(c3, bh[3], h1, 0, 0, 0);        \
    _Pragma("unroll")                                                           \
    for (int ri = 0; ri < 4; ++ri) {                                            \
      float hsum = h0[ri] + h1[ri];                                             \
      float e2 = __expf(2.f * hsum);                                            \
      float ht = 1.f - 2.f / (e2 + 1.f); /* overflow-safe tanh */               \
      float hn = (1.f - zs[ri]) * hd[ri] + zs[ri] * ht;                         \
      hs_out[((size_t)(b0 + quad * 4 + ri) * Tc + (TT)) * Hc + col] = hn;       \
      float gn = (float)SBUF[ri][0];                                            \
      pz[ri] = (float)SBUF[ri][1];                                              \
      pr[ri] = (float)SBUF[ri][2];                                              \
      ph[ri] = (float)SBUF[ri][3];                                              \
      hd[ri] = gn * hn; /* hd for step t+1 */                                   \
      hA[(quad * 4 + ri) * 136 + col] = (_Float16)hd[ri];                       \
    }                                                                           \
    {                                                                           \
      int tl = ((TT) + 3 < Tc) ? (TT) + 3 : Tc - 1;                             \
      _Pragma("unroll")                                                         \
      for (int ri = 0; ri < 4; ++ri)                                            \
        SBUF[ri] = *reinterpret_cast<const h4*>(                                \
            pbase + (size_t)tl * strideT + (size_t)ri * (Hc * 4));              \
    }                                                                           \
  } while (0)

  for (int t = 0; t < Tc; t += 2) {
    #pragma unroll
    for (int kt = 0; kt < 4; ++kt) { keep(bz[kt]); keep(br[kt]); keep(bh[kt]); }
    STEP(t, s1);
    STEP(t + 1, s2);
  }
#undef STEP
}

// ---------------------------------------------------------------------------
// K4: ys = sigmoid(hs @ w_hy + b_hy) via MFMA bf16 (unchanged).
// ---------------------------------------------------------------------------
__global__ __launch_bounds__(256) void k_y(const float* __restrict__ hs,
                                           const unsigned short* __restrict__ hyT,
                                           const float* __restrict__ b_hy,
                                           float* __restrict__ ys) {
  __shared__ unsigned short A16[64 * 136];
  const int tid = threadIdx.x;
  const int r0 = blockIdx.x * 64;
  const int w = tid >> 6, lane = tid & 63, quad = lane >> 4, l16 = lane & 15;

  #pragma unroll
  for (int i = 0; i < 8; ++i) {
    int e = tid + i * 256;
    int row = e >> 5, k4 = (e & 31) * 4;
    float4 hv = *reinterpret_cast<const float4*>(&hs[(size_t)(r0 + row) * Hc + k4]);
    unsigned short s0 = f2b(hv.x), s1 = f2b(hv.y), s2 = f2b(hv.z), s3 = f2b(hv.w);
    unsigned int lo = (unsigned int)s0 | ((unsigned int)s1 << 16);
    unsigned int hi = (unsigned int)s2 | ((unsigned int)s3 << 16);
    *reinterpret_cast<uint2*>(&A16[row * 136 + k4]) = make_uint2(lo, hi);
  }
  __syncthreads();

  f32x4 acc[4];
  #pragma unroll
  for (int mt = 0; mt < 4; ++mt) acc[mt] = {0.f, 0.f, 0.f, 0.f};
  #pragma unroll
  for (int kt = 0; kt < 4; ++kt) {
    bf16x8 bb = *reinterpret_cast<const bf16x8*>(hyT + (w * 16 + l16) * 128 + kt * 32 + quad * 8);
    #pragma unroll
    for (int mt = 0; mt < 4; ++mt) {
      bf16x8 a = *reinterpret_cast<const bf16x8*>(&A16[(mt * 16 + l16) * 136 + kt * 32 + quad * 8]);
      acc[mt] = __builtin_amdgcn_mfma_f32_16x16x32_bf16(a, bb, acc[mt], 0, 0, 0);
    }
  }
  int col = w * 16 + l16;
  float bias = b_hy[col];
  #pragma unroll
  for (int mt = 0; mt < 4; ++mt)
    #pragma unroll
    for (int r = 0; r < 4; ++r) {
      int row = mt * 16 + quad * 4 + r;
      ys[(size_t)(r0 + row) * Oc + col] = 1.f / (1.f + __expf(-(acc[mt][r] + bias)));
    }
}

// ---------------------------------------------------------------------------
extern "C" void kernel_launch(void* const* d_in, const int* in_sizes, int n_in,
                              void* d_out, int out_size, void* d_ws, size_t ws_size,
                              hipStream_t stream) {
  const float* input  = (const float*)d_in[0];
  const float* x_mean = (const float*)d_in[1];
  const float* lastx  = (const float*)d_in[2];
  const float* w_dg_x = (const float*)d_in[3];
  const float* b_dg_x = (const float*)d_in[4];
  const float* w_dg_h = (const float*)d_in[5];
  const float* b_dg_h = (const float*)d_in[6];
  const float* w_xz   = (const float*)d_in[7];
  const float* w_hz   = (const float*)d_in[8];
  const float* w_mz   = (const float*)d_in[9];
  const float* b_mz   = (const float*)d_in[10];
  const float* w_xr   = (const float*)d_in[11];
  const float* w_hr   = (const float*)d_in[12];
  const float* w_mr   = (const float*)d_in[13];
  const float* w_xh   = (const float*)d_in[14];
  const float* w_hh   = (const float*)d_in[15];
  const float* w_mh   = (const float*)d_in[16];
  const float* b_mh   = (const float*)d_in[17];
  const float* w_hy   = (const float*)d_in[18];
  const float* b_hy   = (const float*)d_in[19];

  float* ys = (float*)d_out;                          // (B,T,O)
  float* hs = (float*)d_out + (size_t)Bc * Tc * Oc;   // (B,T,H)

  const size_t BTC = (size_t)Bc * Tc * Cc;            // 8,388,608
  const size_t BTH = (size_t)Bc * Tc * Hc;            // 16,777,216

  float* xlast = (float*)d_ws;
  _Float16* P4 = (_Float16*)(xlast + BTC);            // [T][B][H][4] fp16
  unsigned short* wdgT = (unsigned short*)(P4 + BTH * 4);
  unsigned short* w2T  = wdgT + 192 * 64;
  unsigned short* hyT  = w2T + 384 * 128;
  _Float16* whT16 = (_Float16*)(hyT + 64 * 128);      // 3*128*128 fp16

  k_wprep<<<464, 256, 0, stream>>>(w_dg_x, w_dg_h, w_xz, w_mz, w_xr, w_mr,
                                   w_xh, w_mh, w_hy, w_hz, w_hr, w_hh,
                                   wdgT, w2T, hyT, whT16);
  k_scan<<<Bc, 256, 0, stream>>>(input, lastx, xlast);
  k_pre<<<(Bc * Tc) / 64, 256, 0, stream>>>(input, x_mean, xlast,
                                            b_dg_x, b_dg_h, b_mz, b_mh,
                                            wdgT, w2T, P4);
  k_seq<<<Bc / 16, 512, 0, stream>>>(P4, whT16, hs);
  k_y<<<(Bc * Tc) / 64, 256, 0, stream>>>(hs, hyT, b_hy, ys);
}

// Round 4
// 710.231 us; speedup vs baseline: 1.4278x; 1.4278x over previous
//
#include <hip/hip_runtime.h>
#include <cstdint>

#define Bc 256
#define Cc 64
#define Hc 128
#define Oc 64
#define Tc 512

typedef short bf16x8 __attribute__((ext_vector_type(8)));
typedef float f32x4 __attribute__((ext_vector_type(4)));
typedef _Float16 h2v __attribute__((ext_vector_type(2)));
typedef _Float16 h4 __attribute__((ext_vector_type(4)));

static __device__ __forceinline__ unsigned short f2b(float f) {
  unsigned u = __float_as_uint(f);
  unsigned r = u + 0x7FFFu + ((u >> 16) & 1u);   // RNE
  return (unsigned short)(r >> 16);
}

// packed fp16 dot2 with fp32 accumulate (v_dot2_f32_f16)
static __device__ __forceinline__ float dot2f(unsigned int a, unsigned int b, float c) {
  h2v av = __builtin_bit_cast(h2v, a);
  h2v bv = __builtin_bit_cast(h2v, b);
#if __has_builtin(__builtin_amdgcn_fdot2)
  return __builtin_amdgcn_fdot2(av, bv, c, false);
#else
  return c + (float)av[0] * (float)bv[0] + (float)av[1] * (float)bv[1];
#endif
}

static __device__ __forceinline__ float sigf(float x) {
  return 1.f / (1.f + __expf(-x));   // overflow-safe: exp->inf -> 0
}

// ---------------------------------------------------------------------------
// K0: weight prep.
//  wdgT [192][64] bf16, w2T [384][128] bf16, hyT [64][128] bf16
//  whT  [3][128][64] packed-fp16 pairs: [g][j][kk] = (w_h*[2kk][j], w_h*[2kk+1][j])
// ---------------------------------------------------------------------------
__global__ __launch_bounds__(256) void k_wprep(
    const float* __restrict__ w_dg_x, const float* __restrict__ w_dg_h,
    const float* __restrict__ w_xz, const float* __restrict__ w_mz,
    const float* __restrict__ w_xr, const float* __restrict__ w_mr,
    const float* __restrict__ w_xh, const float* __restrict__ w_mh,
    const float* __restrict__ w_hy,
    const float* __restrict__ w_hz, const float* __restrict__ w_hr,
    const float* __restrict__ w_hh,
    unsigned short* __restrict__ wdgT, unsigned short* __restrict__ w2T,
    unsigned short* __restrict__ hyT, unsigned int* __restrict__ whT) {
  int e = blockIdx.x * 256 + threadIdx.x;
  if (e < 12288) {                       // wdgT: 192 x 64
    int n = e >> 6, k = e & 63;
    float v = (n < 64) ? w_dg_x[k * Cc + n] : w_dg_h[k * Hc + (n - 64)];
    wdgT[e] = f2b(v);
  } else if (e < 61440) {                // w2T: 384 x 128
    int i = e - 12288;
    int n = i >> 7, k = i & 127;
    int gate = n >> 7, nc = n & 127;
    const float* wx = (gate == 0) ? w_xz : (gate == 1) ? w_xr : w_xh;
    const float* wm = (gate == 0) ? w_mz : (gate == 1) ? w_mr : w_mh;
    float v = (k < 64) ? wx[k * Hc + nc] : wm[(k - 64) * Hc + nc];
    w2T[i] = f2b(v);
  } else if (e < 69632) {                // hyT: 64 x 128
    int i = e - 61440;
    int n = i >> 7, k = i & 127;
    hyT[i] = f2b(w_hy[k * Oc + n]);
  } else if (e < 94208) {                // whT: 3 x 128 x 64 packed fp16
    int i = e - 69632;
    int g = i >> 13, rem = i & 8191;
    int j = rem >> 6, kk = rem & 63;
    const float* wh_ = (g == 0) ? w_hz : (g == 1) ? w_hr : w_hh;
    h2v p;
    p[0] = (_Float16)wh_[(2 * kk) * Hc + j];
    p[1] = (_Float16)wh_[(2 * kk + 1) * Hc + j];
    whT[i] = __builtin_bit_cast(unsigned int, p);
  }
}

// ---------------------------------------------------------------------------
// K1: segmented x_last select-scan (unchanged).
// ---------------------------------------------------------------------------
__global__ __launch_bounds__(256) void k_scan(const float* __restrict__ input,
                                              const float* __restrict__ lastx,
                                              float* __restrict__ xlast) {
  const int b = blockIdx.x;
  const int seg = threadIdx.x >> 6;
  const int c = threadIdx.x & 63;
  const int tb = seg * 128;
  __shared__ float segval[4][64];
  __shared__ int   segvld[4][64];
  __shared__ float segcin[4][64];
  const float* xp = input + ((size_t)(b * 3 + 0) * Cc + c) * Tc;
  const float* mp = input + ((size_t)(b * 3 + 1) * Cc + c) * Tc;

  float val = 0.f; int vld = 0;
  for (int t = tb + 127; t >= tb; --t) {
    if (mp[t] > 0.f) { val = xp[t]; vld = 1; break; }
  }
  segval[seg][c] = val; segvld[seg][c] = vld;
  __syncthreads();
  if (threadIdx.x < 64) {
    float carry = lastx[b * Cc + threadIdx.x];
    #pragma unroll
    for (int s = 0; s < 4; ++s) {
      segcin[s][threadIdx.x] = carry;
      if (segvld[s][threadIdx.x]) carry = segval[s][threadIdx.x];
    }
  }
  __syncthreads();
  float cur = segcin[seg][c];
  float* op = xlast + ((size_t)b * Tc + tb) * Cc + c;
  for (int t = 0; t < 128; t += 4) {
    const float4 m4 = *reinterpret_cast<const float4*>(mp + tb + t);
    const float4 x4 = *reinterpret_cast<const float4*>(xp + tb + t);
    cur = (m4.x > 0.f) ? x4.x : cur; op[(size_t)(t + 0) * Cc] = cur;
    cur = (m4.y > 0.f) ? x4.y : cur; op[(size_t)(t + 1) * Cc] = cur;
    cur = (m4.z > 0.f) ? x4.z : cur; op[(size_t)(t + 2) * Cc] = cur;
    cur = (m4.w > 0.f) ? x4.w : cur; op[(size_t)(t + 3) * Cc] = cur;
  }
}

// ---------------------------------------------------------------------------
// K2: MFMA bf16 pre-compute. Output packed [t][b][H][4] fp16:
//  s=0 gamma_h, s=1 pre_z, s=2 pre_r, s=3 pre_h
// ---------------------------------------------------------------------------
__global__ __launch_bounds__(256) void k_pre(
    const float* __restrict__ input, const float* __restrict__ x_mean,
    const float* __restrict__ xlast,
    const float* __restrict__ b_dg_x, const float* __restrict__ b_dg_h,
    const float* __restrict__ b_mz, const float* __restrict__ b_mh,
    const unsigned short* __restrict__ wdgT, const unsigned short* __restrict__ w2T,
    _Float16* __restrict__ P4) {
  __shared__ unsigned short d16[64 * 72];
  __shared__ unsigned short A16[64 * 136];
  __shared__ float x_cs[64 * 68];
  __shared__ float m_cs[64 * 68];

  const int tid = threadIdx.x;
  const int b = blockIdx.x >> 3;
  const int t0 = (blockIdx.x & 7) * 64;
  const int w = tid >> 6, lane = tid & 63, quad = lane >> 4, l16 = lane & 15;

  #pragma unroll
  for (int i = 0; i < 4; ++i) {
    int e = tid + i * 256;
    int c = e >> 4, t4 = (e & 15) * 4;
    const size_t rx = ((size_t)(b * 3 + 0) * Cc + c) * Tc + t0 + t4;
    const size_t rm = ((size_t)(b * 3 + 1) * Cc + c) * Tc + t0 + t4;
    const size_t rd = ((size_t)(b * 3 + 2) * Cc + c) * Tc + t0 + t4;
    float4 xv = *reinterpret_cast<const float4*>(input + rx);
    float4 mv = *reinterpret_cast<const float4*>(input + rm);
    float4 dv = *reinterpret_cast<const float4*>(input + rd);
    *reinterpret_cast<float4*>(&x_cs[c * 68 + t4]) = xv;
    *reinterpret_cast<float4*>(&m_cs[c * 68 + t4]) = mv;
    A16[(t4 + 0) * 136 + 64 + c] = f2b(mv.x);
    A16[(t4 + 1) * 136 + 64 + c] = f2b(mv.y);
    A16[(t4 + 2) * 136 + 64 + c] = f2b(mv.z);
    A16[(t4 + 3) * 136 + 64 + c] = f2b(mv.w);
    d16[(t4 + 0) * 72 + c] = f2b(dv.x);
    d16[(t4 + 1) * 72 + c] = f2b(dv.y);
    d16[(t4 + 2) * 72 + c] = f2b(dv.z);
    d16[(t4 + 3) * 72 + c] = f2b(dv.w);
  }
  __syncthreads();

  f32x4 accA[4][3];
  #pragma unroll
  for (int mt = 0; mt < 4; ++mt)
    #pragma unroll
    for (int j = 0; j < 3; ++j) accA[mt][j] = {0.f, 0.f, 0.f, 0.f};
  #pragma unroll
  for (int kt = 0; kt < 2; ++kt) {
    bf16x8 a[4];
    #pragma unroll
    for (int mt = 0; mt < 4; ++mt)
      a[mt] = *reinterpret_cast<const bf16x8*>(&d16[(mt * 16 + l16) * 72 + kt * 32 + quad * 8]);
    #pragma unroll
    for (int j = 0; j < 3; ++j) {
      int nt = w + j * 4;
      bf16x8 bb = *reinterpret_cast<const bf16x8*>(wdgT + (nt * 16 + l16) * 64 + kt * 32 + quad * 8);
      #pragma unroll
      for (int mt = 0; mt < 4; ++mt)
        accA[mt][j] = __builtin_amdgcn_mfma_f32_16x16x32_bf16(a[mt], bb, accA[mt][j], 0, 0, 0);
    }
  }

  {
    int c = w * 16 + l16;
    float xmn = x_mean[b * Cc + c];
    float bx = b_dg_x[c];
    #pragma unroll
    for (int mt = 0; mt < 4; ++mt)
      #pragma unroll
      for (int r = 0; r < 4; ++r) {
        int row = mt * 16 + quad * 4 + r;
        float g = __expf(-fmaxf(accA[mt][0][r] + bx, 0.f));
        float mv = m_cs[c * 68 + row], xv = x_cs[c * 68 + row];
        float xl = xlast[((size_t)b * Tc + t0 + row) * Cc + c];
        float xin = mv * xv + (1.f - mv) * (g * xl + (1.f - g) * xmn);
        A16[row * 136 + c] = f2b(xin);
      }
  }
  #pragma unroll
  for (int j = 1; j < 3; ++j) {
    int nh = (w + j * 4) * 16 - 64 + l16;
    float bh = b_dg_h[nh];
    #pragma unroll
    for (int mt = 0; mt < 4; ++mt)
      #pragma unroll
      for (int r = 0; r < 4; ++r) {
        int row = mt * 16 + quad * 4 + r;
        P4[(((size_t)(t0 + row) * Bc + b) * Hc + nh) * 4 + 0] =
            (_Float16)__expf(-fmaxf(accA[mt][j][r] + bh, 0.f));
      }
  }
  __syncthreads();

  f32x4 accB[4][6];
  #pragma unroll
  for (int mt = 0; mt < 4; ++mt)
    #pragma unroll
    for (int j = 0; j < 6; ++j) accB[mt][j] = {0.f, 0.f, 0.f, 0.f};
  #pragma unroll
  for (int kt = 0; kt < 4; ++kt) {
    bf16x8 a[4];
    #pragma unroll
    for (int mt = 0; mt < 4; ++mt)
      a[mt] = *reinterpret_cast<const bf16x8*>(&A16[(mt * 16 + l16) * 136 + kt * 32 + quad * 8]);
    #pragma unroll
    for (int j = 0; j < 6; ++j) {
      int nt = (j >> 1) * 8 + w + (j & 1) * 4;
      bf16x8 bb = *reinterpret_cast<const bf16x8*>(w2T + (nt * 16 + l16) * 128 + kt * 32 + quad * 8);
      #pragma unroll
      for (int mt = 0; mt < 4; ++mt)
        accB[mt][j] = __builtin_amdgcn_mfma_f32_16x16x32_bf16(a[mt], bb, accB[mt][j], 0, 0, 0);
    }
  }
  #pragma unroll
  for (int j = 0; j < 6; ++j) {
    int nt = (j >> 1) * 8 + w + (j & 1) * 4;
    int gate = nt >> 3;
    int col = (nt & 7) * 16 + l16;
    float bias = (gate == 0) ? b_mz[col] : (gate == 2) ? b_mh[col] : 0.f;
    #pragma unroll
    for (int mt = 0; mt < 4; ++mt)
      #pragma unroll
      for (int r = 0; r < 4; ++r) {
        int row = mt * 16 + quad * 4 + r;
        P4[(((size_t)(t0 + row) * Bc + b) * Hc + col) * 4 + gate + 1] =
            (_Float16)(accB[mt][j][r] + bias);
      }
  }
}

// ---------------------------------------------------------------------------
// K3: sequential h-recurrence — 2-barrier role-split scalar design.
// 256 blocks (1 batch each) x 256 threads (4 waves, 1/SIMD).
// waves 0-1 (role z/owner, col j=tid&127): P1 full-K z-dot; P2 full-K h~-dot,
//   tanh, h-update, hd16 publish. Owns h_j in registers.
// waves 2-3 (role r, col j): P1 full-K r-dot + publish r*hd; P2 idle.
// All dot operands are wave-uniform uint4 LDS broadcasts (conflict-free).
// 2 barriers/step. 4 independent dot accumulators (16-deep chains).
// Stream prefetch distance 2 via rotating h4 buffers.
// ---------------------------------------------------------------------------
__global__ __launch_bounds__(256, 1) void k_seq(
    const _Float16* __restrict__ P4,    // [T][B][H][4] fp16 {gamma,pz,pr,ph}
    const unsigned int* __restrict__ whT,  // [3][128][64] packed fp16 pairs
    float* __restrict__ hs_out) {
  const int tid = threadIdx.x;
  const int b = blockIdx.x;
  const int j = tid & 127;
  const bool zrole = (tid >> 7) == 0;   // waves 0,1: z/owner; waves 2,3: r

  __shared__ _Float16 hd16[128];
  __shared__ _Float16 rhd16[128];

  // Weights: z-wave loads wz(g0)+wh(g2); r-wave loads wr(g1) into wa.
  uint4 wa[16], wb[16];
  {
    const uint4* pz_ = reinterpret_cast<const uint4*>(whT + 0 * 8192 + j * 64);
    const uint4* pr_ = reinterpret_cast<const uint4*>(whT + 1 * 8192 + j * 64);
    const uint4* ph_ = reinterpret_cast<const uint4*>(whT + 2 * 8192 + j * 64);
    if (zrole) {
      #pragma unroll
      for (int i = 0; i < 16; ++i) { wa[i] = pz_[i]; wb[i] = ph_[i]; }
    } else {
      #pragma unroll
      for (int i = 0; i < 16; ++i) { wa[i] = pr_[i]; wb[i] = pr_[i]; }
    }
  }

  if (tid < 128) hd16[tid] = (_Float16)0.f;

  const size_t strideT = (size_t)Bc * Hc * 4;
  const _Float16* pbase = P4 + (((size_t)b) * Hc + j) * 4;
  const size_t hb = (size_t)b * Tc * Hc;

  float pvz, pvr, pvh, h_reg = 0.f, hd_reg = 0.f;
  h4 s1, s2;
  {
    h4 s0 = *reinterpret_cast<const h4*>(pbase);
    pvz = (float)s0[1]; pvr = (float)s0[2]; pvh = (float)s0[3];
    s1 = *reinterpret_cast<const h4*>(pbase + strideT);
    s2 = *reinterpret_cast<const h4*>(pbase + 2 * strideT);
  }
  __syncthreads();

  const uint4* hp4 = reinterpret_cast<const uint4*>(hd16);
  const uint4* rp4 = reinterpret_cast<const uint4*>(rhd16);

#define STEP(TT, SBUF)                                                          \
  do {                                                                          \
    /* ---- P1: z-dot (z-waves) / r-dot + rhd publish (r-waves) ---- */         \
    float a0 = 0.f, a1 = 0.f, a2 = 0.f, a3 = 0.f;                               \
    _Pragma("unroll")                                                           \
    for (int i = 0; i < 16; i += 4) {                                           \
      uint4 h0 = hp4[i], h1 = hp4[i + 1], h2 = hp4[i + 2], h3 = hp4[i + 3];     \
      a0 = dot2f(h0.x, wa[i].x, a0);     a1 = dot2f(h0.y, wa[i].y, a1);         \
      a2 = dot2f(h0.z, wa[i].z, a2);     a3 = dot2f(h0.w, wa[i].w, a3);         \
      a0 = dot2f(h1.x, wa[i + 1].x, a0); a1 = dot2f(h1.y, wa[i + 1].y, a1);     \
      a2 = dot2f(h1.z, wa[i + 1].z, a2); a3 = dot2f(h1.w, wa[i + 1].w, a3);     \
      a0 = dot2f(h2.x, wa[i + 2].x, a0); a1 = dot2f(h2.y, wa[i + 2].y, a1);     \
      a2 = dot2f(h2.z, wa[i + 2].z, a2); a3 = dot2f(h2.w, wa[i + 2].w, a3);     \
      a0 = dot2f(h3.x, wa[i + 3].x, a0); a1 = dot2f(h3.y, wa[i + 3].y, a1);     \
      a2 = dot2f(h3.z, wa[i + 3].z, a2); a3 = dot2f(h3.w, wa[i + 3].w, a3);     \
    }                                                                           \
    float dsum = (a0 + a1) + (a2 + a3);                                         \
    float z_reg = 0.f;                                                          \
    if (zrole) {                                                                \
      z_reg = sigf(pvz + dsum);                                                 \
    } else {                                                                    \
      float r = sigf(pvr + dsum);                                               \
      rhd16[j] = (_Float16)(r * (float)hd16[j]);                                \
    }                                                                           \
    __syncthreads(); /* B1: rhd16 ready; hd16 reads done */                     \
    /* ---- P2: h~-dot + update (z-waves only) ---- */                          \
    if (zrole) {                                                                \
      float c0 = 0.f, c1 = 0.f, c2 = 0.f, c3 = 0.f;                             \
      _Pragma("unroll")                                                         \
      for (int i = 0; i < 16; i += 4) {                                         \
        uint4 r0 = rp4[i], r1 = rp4[i + 1], r2 = rp4[i + 2], r3 = rp4[i + 3];   \
        c0 = dot2f(r0.x, wb[i].x, c0);     c1 = dot2f(r0.y, wb[i].y, c1);       \
        c2 = dot2f(r0.z, wb[i].z, c2);     c3 = dot2f(r0.w, wb[i].w, c3);       \
        c0 = dot2f(r1.x, wb[i + 1].x, c0); c1 = dot2f(r1.y, wb[i + 1].y, c1);   \
        c2 = dot2f(r1.z, wb[i + 1].z, c2); c3 = dot2f(r1.w, wb[i + 1].w, c3);   \
        c0 = dot2f(r2.x, wb[i + 2].x, c0); c1 = dot2f(r2.y, wb[i + 2].y, c1);   \
        c2 = dot2f(r2.z, wb[i + 2].z, c2); c3 = dot2f(r2.w, wb[i + 2].w, c3);   \
        c0 = dot2f(r3.x, wb[i + 3].x, c0); c1 = dot2f(r3.y, wb[i + 3].y, c1);   \
        c2 = dot2f(r3.z, wb[i + 3].z, c2); c3 = dot2f(r3.w, wb[i + 3].w, c3);   \
      }                                                                         \
      float hsum = pvh + (c0 + c1) + (c2 + c3);                                 \
      float e2 = __expf(2.f * hsum);                                            \
      float ht = 1.f - 2.f / (e2 + 1.f);   /* overflow-safe tanh */             \
      float hn = (1.f - z_reg) * hd_reg + z_reg * ht;                           \
      hs_out[hb + (size_t)(TT) * Hc + j] = hn;                                  \
      h_reg = hn;                                                               \
      float gn = (float)SBUF[0];           /* gamma(t+1) */                     \
      hd_reg = gn * hn;                                                         \
      hd16[j] = (_Float16)hd_reg;                                               \
    }                                                                           \
    pvz = (float)SBUF[1]; pvr = (float)SBUF[2]; pvh = (float)SBUF[3];           \
    {                                                                           \
      int tl = ((TT) + 3 < Tc) ? (TT) + 3 : Tc - 1;                             \
      SBUF = *reinterpret_cast<const h4*>(pbase + (size_t)tl * strideT);        \
    }                                                                           \
    __syncthreads(); /* B2: hd16(t+1) ready; rhd16 reads done */                \
  } while (0)

  for (int t = 0; t < Tc; t += 2) {
    STEP(t, s1);
    STEP(t + 1, s2);
  }
#undef STEP
}

// ---------------------------------------------------------------------------
// K4: ys = sigmoid(hs @ w_hy + b_hy) via MFMA bf16 (unchanged).
// ---------------------------------------------------------------------------
__global__ __launch_bounds__(256) void k_y(const float* __restrict__ hs,
                                           const unsigned short* __restrict__ hyT,
                                           const float* __restrict__ b_hy,
                                           float* __restrict__ ys) {
  __shared__ unsigned short A16[64 * 136];
  const int tid = threadIdx.x;
  const int r0 = blockIdx.x * 64;
  const int w = tid >> 6, lane = tid & 63, quad = lane >> 4, l16 = lane & 15;

  #pragma unroll
  for (int i = 0; i < 8; ++i) {
    int e = tid + i * 256;
    int row = e >> 5, k4 = (e & 31) * 4;
    float4 hv = *reinterpret_cast<const float4*>(&hs[(size_t)(r0 + row) * Hc + k4]);
    unsigned short s0 = f2b(hv.x), s1 = f2b(hv.y), s2 = f2b(hv.z), s3 = f2b(hv.w);
    unsigned int lo = (unsigned int)s0 | ((unsigned int)s1 << 16);
    unsigned int hi = (unsigned int)s2 | ((unsigned int)s3 << 16);
    *reinterpret_cast<uint2*>(&A16[row * 136 + k4]) = make_uint2(lo, hi);
  }
  __syncthreads();

  f32x4 acc[4];
  #pragma unroll
  for (int mt = 0; mt < 4; ++mt) acc[mt] = {0.f, 0.f, 0.f, 0.f};
  #pragma unroll
  for (int kt = 0; kt < 4; ++kt) {
    bf16x8 bb = *reinterpret_cast<const bf16x8*>(hyT + (w * 16 + l16) * 128 + kt * 32 + quad * 8);
    #pragma unroll
    for (int mt = 0; mt < 4; ++mt) {
      bf16x8 a = *reinterpret_cast<const bf16x8*>(&A16[(mt * 16 + l16) * 136 + kt * 32 + quad * 8]);
      acc[mt] = __builtin_amdgcn_mfma_f32_16x16x32_bf16(a, bb, acc[mt], 0, 0, 0);
    }
  }
  int col = w * 16 + l16;
  float bias = b_hy[col];
  #pragma unroll
  for (int mt = 0; mt < 4; ++mt)
    #pragma unroll
    for (int r = 0; r < 4; ++r) {
      int row = mt * 16 + quad * 4 + r;
      ys[(size_t)(r0 + row) * Oc + col] = 1.f / (1.f + __expf(-(acc[mt][r] + bias)));
    }
}

// ---------------------------------------------------------------------------
extern "C" void kernel_launch(void* const* d_in, const int* in_sizes, int n_in,
                              void* d_out, int out_size, void* d_ws, size_t ws_size,
                              hipStream_t stream) {
  const float* input  = (const float*)d_in[0];
  const float* x_mean = (const float*)d_in[1];
  const float* lastx  = (const float*)d_in[2];
  const float* w_dg_x = (const float*)d_in[3];
  const float* b_dg_x = (const float*)d_in[4];
  const float* w_dg_h = (const float*)d_in[5];
  const float* b_dg_h = (const float*)d_in[6];
  const float* w_xz   = (const float*)d_in[7];
  const float* w_hz   = (const float*)d_in[8];
  const float* w_mz   = (const float*)d_in[9];
  const float* b_mz   = (const float*)d_in[10];
  const float* w_xr   = (const float*)d_in[11];
  const float* w_hr   = (const float*)d_in[12];
  const float* w_mr   = (const float*)d_in[13];
  const float* w_xh   = (const float*)d_in[14];
  const float* w_hh   = (const float*)d_in[15];
  const float* w_mh   = (const float*)d_in[16];
  const float* b_mh   = (const float*)d_in[17];
  const float* w_hy   = (const float*)d_in[18];
  const float* b_hy   = (const float*)d_in[19];

  float* ys = (float*)d_out;                          // (B,T,O)
  float* hs = (float*)d_out + (size_t)Bc * Tc * Oc;   // (B,T,H)

  const size_t BTC = (size_t)Bc * Tc * Cc;            // 8,388,608
  const size_t BTH = (size_t)Bc * Tc * Hc;            // 16,777,216

  float* xlast = (float*)d_ws;
  _Float16* P4 = (_Float16*)(xlast + BTC);            // [T][B][H][4] fp16
  unsigned short* wdgT = (unsigned short*)(P4 + BTH * 4);
  unsigned short* w2T  = wdgT + 192 * 64;
  unsigned short* hyT  = w2T + 384 * 128;
  unsigned int*   whT  = (unsigned int*)(hyT + 64 * 128);  // 3*128*64 packed fp16

  k_wprep<<<368, 256, 0, stream>>>(w_dg_x, w_dg_h, w_xz, w_mz, w_xr, w_mr,
                                   w_xh, w_mh, w_hy, w_hz, w_hr, w_hh,
                                   wdgT, w2T, hyT, whT);
  k_scan<<<Bc, 256, 0, stream>>>(input, lastx, xlast);
  k_pre<<<(Bc * Tc) / 64, 256, 0, stream>>>(input, x_mean, xlast,
                                            b_dg_x, b_dg_h, b_mz, b_mh,
                                            wdgT, w2T, P4);
  k_seq<<<Bc, 256, 0, stream>>>(P4, whT, hs);
  k_y<<<(Bc * Tc) / 64, 256, 0, stream>>>(hs, hyT, b_hy, ys);
}